// Round 4
// baseline (150.288 us; speedup 1.0000x reference)
//
#include <hip/hip_runtime.h>

#define QMAX 127.0f

typedef int v4i __attribute__((ext_vector_type(4)));
typedef int v16i __attribute__((ext_vector_type(16)));

__device__ __forceinline__ void gload_lds16(const void* g, void* l) {
  __builtin_amdgcn_global_load_lds(
      (const __attribute__((address_space(1))) void*)g,
      (__attribute__((address_space(3))) void*)l, 16, 0, 0);
}

// ---------------- merged prep: pack W0/W1/W2 + quantize x (1 launch) --------
__device__ __forceinline__ void pack_body(const int* __restrict__ W,
                                          signed char* __restrict__ W8,
                                          int* __restrict__ bias,
                                          unsigned lblk, int kshift) {
  unsigned t = lblk * 256u + threadIdx.x;
  unsigned row = t >> kshift;
  unsigned j = t & ((1u << kshift) - 1u);
  unsigned K = 4u << kshift;
  size_t srcBase = (size_t)row * (size_t)(K + 1) + (size_t)j * 4;
  int c0 = W[srcBase + 0], c1 = W[srcBase + 1], c2 = W[srcBase + 2], c3 = W[srcBase + 3];
  unsigned packed = (unsigned)(c0 & 0xff) | ((unsigned)(c1 & 0xff) << 8) |
                    ((unsigned)(c2 & 0xff) << 16) | ((unsigned)(c3 & 0xff) << 24);
  reinterpret_cast<unsigned*>(W8)[t] = packed;
  if (j == 0) bias[row] = W[(size_t)row * (K + 1) + K];
}

__global__ void prep_kernel(const float* __restrict__ x,
                            signed char* __restrict__ qa0,
                            const float* __restrict__ pAin,
                            const int* __restrict__ W0, signed char* __restrict__ W0p, int* __restrict__ b0,
                            const int* __restrict__ W1, signed char* __restrict__ W1p, int* __restrict__ b1,
                            const int* __restrict__ W2, signed char* __restrict__ W2p, int* __restrict__ b2) {
  unsigned blk = blockIdx.x;
  if (blk < 4096u) {
    pack_body(W0, W0p, b0, blk, 8);
  } else if (blk < 20480u) {
    pack_body(W1, W1p, b1, blk - 4096u, 10);
  } else if (blk < 24576u) {
    pack_body(W2, W2p, b2, blk - 20480u, 10);
  } else {
    unsigned t = (blk - 24576u) * 256u + threadIdx.x;
    float s = QMAX / pAin[0];
    float4 v = reinterpret_cast<const float4*>(x)[t];
    int q0 = (int)fminf(fmaxf(rintf(v.x * s), -QMAX), QMAX);
    int q1 = (int)fminf(fmaxf(rintf(v.y * s), -QMAX), QMAX);
    int q2 = (int)fminf(fmaxf(rintf(v.z * s), -QMAX), QMAX);
    int q3 = (int)fminf(fmaxf(rintf(v.w * s), -QMAX), QMAX);
    unsigned packed = (unsigned)(q0 & 0xff) | ((unsigned)(q1 & 0xff) << 8) |
                      ((unsigned)(q2 & 0xff) << 16) | ((unsigned)(q3 & 0xff) << 24);
    reinterpret_cast<unsigned*>(qa0)[t] = packed;
  }
}

// =====================================================================
// 256x256-tile 8-phase int8 GEMM, 32x32x32 MFMA, kc-partitioned phases.
// 8 waves (2M x 4N); per-wave out 128x64 = 4mf x 2nf fragments of 32x32.
// BK=128 B -> kc=0..3 chunks of K=32. Per phase: 8 MFMA + {8,8,4,4}
// ds_read_b128 issued ONE PHASE AHEAD of their consuming MFMA (ping-pong
// A-sets aP/aQ; single bF[2][4] with phase-disjoint lifetimes).
// Stage ordering, VMC6 points (ph4/ph8, 3-phase slack), and LGK0 closes
// (ph1/3/5/7) identical to the round-2/3 verified schedule.
// =====================================================================

#define FENCE() asm volatile("" ::: "memory")
#define BARRIER()                      \
  do {                                 \
    FENCE();                           \
    __builtin_amdgcn_s_barrier();      \
    FENCE();                           \
  } while (0)
#define LGK0() asm volatile("s_waitcnt lgkmcnt(0)" ::: "memory")
#define VMC6() asm volatile("s_waitcnt vmcnt(6)" ::: "memory")
#define VMC0() asm volatile("s_waitcnt vmcnt(0)" ::: "memory")

#define STAGE_A(bf, h, t)                                                     \
  do {                                                                        \
    const signed char* _g = gA + (size_t)((h) * 128) * K + (size_t)(t) * 128; \
    signed char* _l = ldsA + (bf) * 32768 + (h) * 16384 + ldsThr;             \
    gload_lds16(_g, _l);                                                      \
    gload_lds16(_g + (size_t)8 * K, _l + 1024);                               \
  } while (0)

#define STAGE_B(bf, h, t)                                                     \
  do {                                                                        \
    const signed char* _g = gB + (size_t)((h) * 128) * K + (size_t)(t) * 128; \
    signed char* _l = ldsB + (bf) * 32768 + (h) * 16384 + ldsThr;             \
    gload_lds16(_g, _l);                                                      \
    gload_lds16(_g + (size_t)8 * K, _l + 1024);                               \
  } while (0)

// 4 ds_read_b128: all A fragments (mf=0..3) for k-chunk kc -> dst[0..3]
#define LDA4(bf, kc, dst)                                                     \
  do {                                                                        \
    _Pragma("unroll") for (int mf = 0; mf < 4; ++mf) {                        \
      int row = wm * 128 + mf * 32 + l31;                                     \
      int off = ((kc) * 32 + hk * 16) ^ ((row & 7) << 4);                     \
      dst[mf] = *(const v4i*)(ldsA + (bf) * 32768 + row * 128 + off);         \
    }                                                                         \
  } while (0)

// 2 ds_read_b128: both B fragments (nf=0..1) for k-chunk kc -> bF[nf][kc]
#define LDB2(bf, kc)                                                          \
  do {                                                                        \
    _Pragma("unroll") for (int nf = 0; nf < 2; ++nf) {                        \
      int row = wn * 64 + nf * 32 + l31;                                      \
      int off = ((kc) * 32 + hk * 16) ^ ((row & 7) << 4);                     \
      bF[nf][kc] = *(const v4i*)(ldsB + (bf) * 32768 + row * 128 + off);      \
    }                                                                         \
  } while (0)

// 8 MFMA (4mf x 2nf) for k-chunk kc with A-set aset
#define MFMA8(aset, kc)                                                       \
  do {                                                                        \
    __builtin_amdgcn_s_setprio(1);                                            \
    _Pragma("unroll") for (int mf = 0; mf < 4; ++mf)                          \
    _Pragma("unroll") for (int nf = 0; nf < 2; ++nf)                          \
      acc[mf][nf] = __builtin_amdgcn_mfma_i32_32x32x32_i8(                    \
          aset[mf], bF[nf][kc], acc[mf][nf], 0, 0, 0);                        \
    __builtin_amdgcn_s_setprio(0);                                            \
  } while (0)

__global__ __launch_bounds__(512, 2)
void qgemm256_kernel(const signed char* __restrict__ A,
                     const signed char* __restrict__ Bw,
                     const int* __restrict__ bias,
                     signed char* __restrict__ O,
                     int N, int K, int nbn,
                     const float* __restrict__ pAin,
                     const float* __restrict__ pAw,
                     const float* __restrict__ pAnext) {
  extern __shared__ signed char lds[];
  signed char* ldsA = lds;           // buf0 [0,32K), buf1 [32K,64K)
  signed char* ldsB = lds + 65536;

  const int nwg = gridDim.x, bid = blockIdx.x, per = nwg >> 3;
  const int swz = (bid & 7) * per + (bid >> 3);
  const int brow = swz / nbn, bcol = swz - brow * nbn;
  const int browBase = brow << 8, bcolBase = bcol << 8;

  const int tid = threadIdx.x;
  const int lane = tid & 63, l31 = lane & 31, hk = lane >> 5;
  const int wid = tid >> 6, wm = wid >> 2, wn = wid & 3;

  const int rloc = (wid << 4) + (lane >> 3);
  const int csrc = (lane & 7) ^ ((lane >> 3) & 7);
  const signed char* gA = A + (size_t)(browBase + rloc) * K + csrc * 16;
  const signed char* gB = Bw + (size_t)(bcolBase + rloc) * K + csrc * 16;
  const int ldsThr = (wid << 11) + lane * 16;

  v16i acc[4][2] = {};
  v4i aP[4], aQ[4], bF[2][4];

  const int nk = K >> 7, niter = nk >> 1, nkm = nk - 1;

  // prologue: t0 {B0,B1,A0,A1}, t1 {B0,B1,A0}; 3 half-tiles stay in flight.
  STAGE_B(0, 0, 0); STAGE_B(0, 1, 0); STAGE_A(0, 0, 0); STAGE_A(0, 1, 0);
  STAGE_B(1, 0, 1); STAGE_B(1, 1, 1); STAGE_A(1, 0, 1);
  VMC6();
  BARRIER();
  // ph8'-slot reads: buf0 kc0 A -> aP, B kc0/kc1
  LDA4(0, 0, aP);
  LDB2(0, 0); LDB2(0, 1);

#pragma unroll 1
  for (int i = 0; i < niter; ++i) {
    const int t1 = 2 * i + 1;
    const int tE = (2 * i + 2) & nkm;   // wrapped: always issue (exact vmcnt)
    const int tO = (2 * i + 3) & nkm;
    // ph1: MFMA buf0.kc0; reads A.kc1->aQ, B.kc2, B.kc3
    STAGE_A(1, 1, t1);
    BARRIER();
    LDA4(0, 1, aQ); LDB2(0, 2); LDB2(0, 3);
    MFMA8(aP, 0);
    LGK0();            // buf0.B reads drained before ph2 stages buf0.B
    BARRIER();
    // ph2: MFMA buf0.kc1; reads A.kc2->aP
    STAGE_B(0, 0, tE);
    BARRIER();
    LDA4(0, 2, aP);
    MFMA8(aQ, 1);
    BARRIER();
    // ph3: MFMA buf0.kc2; reads A.kc3->aQ
    STAGE_B(0, 1, tE);
    BARRIER();
    LDA4(0, 3, aQ);
    MFMA8(aP, 2);
    LGK0();            // buf0.A reads drained before ph4 stages buf0.A
    BARRIER();
    // ph4: MFMA buf0.kc3; reads buf1 kc0 A->aP, B kc0/kc1 (buf1 valid now)
    STAGE_A(0, 0, tE);
    VMC6();
    BARRIER();
    LDA4(1, 0, aP); LDB2(1, 0); LDB2(1, 1);
    MFMA8(aQ, 3);
    BARRIER();
    // ph5: MFMA buf1.kc0; reads A.kc1->aQ, B.kc2, B.kc3
    STAGE_A(0, 1, tE);
    BARRIER();
    LDA4(1, 1, aQ); LDB2(1, 2); LDB2(1, 3);
    MFMA8(aP, 0);
    LGK0();            // buf1.B reads drained before ph6 stages buf1.B
    BARRIER();
    // ph6: MFMA buf1.kc1; reads A.kc2->aP
    STAGE_B(1, 0, tO);
    BARRIER();
    LDA4(1, 2, aP);
    MFMA8(aQ, 1);
    BARRIER();
    // ph7: MFMA buf1.kc2; reads A.kc3->aQ
    STAGE_B(1, 1, tO);
    BARRIER();
    LDA4(1, 3, aQ);
    MFMA8(aP, 2);
    LGK0();            // buf1.A reads drained before ph8 stages buf1.A
    BARRIER();
    // ph8: MFMA buf1.kc3; reads next-buf0 kc0 A->aP, B kc0/kc1
    STAGE_A(1, 0, tO);
    VMC6();
    BARRIER();
    LDA4(0, 0, aP); LDB2(0, 0); LDB2(0, 1);
    MFMA8(aQ, 3);
    BARRIER();
  }

  VMC0();  // drain orphan prefetches before epilogue

  // epilogue: 32x32 C/D layout: col = lane&31, row = (r&3)+8*(r>>2)+4*(lane>>5)
  const float sDeq = (pAw[0] * pAin[0]) / (QMAX * QMAX);
  const float sQ = QMAX / pAnext[0];
#pragma unroll
  for (int nf = 0; nf < 2; ++nf) {
    const int gcol = bcolBase + wn * 64 + nf * 32 + l31;
    const int bv = bias[gcol];
#pragma unroll
    for (int mf = 0; mf < 4; ++mf) {
      const int growB = browBase + wm * 128 + mf * 32 + 4 * hk;
#pragma unroll
      for (int r = 0; r < 16; ++r) {
        const int grow = growB + (r & 3) + 8 * (r >> 2);
        float f = (float)(acc[mf][nf][r] + bv) * sDeq;
        f = fmaxf(f, 0.0f);
        float qf = fminf(fmaxf(rintf(f * sQ), -QMAX), QMAX);
        O[(size_t)grow * N + gcol] = (signed char)(int)qf;
      }
    }
  }
}

// ---------------- 128x128-tile 2-barrier int8 GEMM (layer 2, f32 out) -------
__global__ __launch_bounds__(256)
void qgemm_kernel(const signed char* __restrict__ A,
                  const signed char* __restrict__ Bw,
                  const int* __restrict__ bias,
                  float* __restrict__ O,
                  int N, int K, int nbn,
                  const float* __restrict__ pAin,
                  const float* __restrict__ pAw) {
  __shared__ signed char slds[32768];
  signed char* ldsA = slds;
  signed char* ldsB = slds + 16384;

  int nwg = gridDim.x;
  int bid = blockIdx.x;
  int per = nwg >> 3;
  int swz = (bid & 7) * per + (bid >> 3);
  int brow = swz / nbn;
  int bcol = swz - brow * nbn;
  int browBase = brow << 7;
  int bcolBase = bcol << 7;

  int tid = threadIdx.x;
  int lane = tid & 63;
  int l15 = lane & 15;
  int hi = lane >> 4;
  int wid = tid >> 6;
  int wr = (wid >> 1) << 6;
  int wc = (wid & 1) << 6;

  v4i acc[4][4] = {};

  int nk = K >> 7;
  for (int kt = 0; kt < nk; ++kt) {
    int k0 = kt << 7;
#pragma unroll
    for (int i = 0; i < 4; ++i) {
      int c = i * 256 + tid;
      int r = c >> 3;
      int osrc = ((c & 7) << 4) ^ ((r & 7) << 4);
      gload_lds16(A + (size_t)(browBase + r) * K + (k0 + osrc), ldsA + c * 16);
      gload_lds16(Bw + (size_t)(bcolBase + r) * K + (k0 + osrc), ldsB + c * 16);
    }
    __syncthreads();
#pragma unroll
    for (int kk = 0; kk < 2; ++kk) {
      v4i a[4], b[4];
#pragma unroll
      for (int m = 0; m < 4; ++m) {
        int row = wr + m * 16 + l15;
        int off = (kk * 64 + hi * 16) ^ ((row & 7) << 4);
        a[m] = *reinterpret_cast<const v4i*>(ldsA + row * 128 + off);
      }
#pragma unroll
      for (int n = 0; n < 4; ++n) {
        int row = wc + n * 16 + l15;
        int off = (kk * 64 + hi * 16) ^ ((row & 7) << 4);
        b[n] = *reinterpret_cast<const v4i*>(ldsB + row * 128 + off);
      }
#pragma unroll
      for (int m = 0; m < 4; ++m)
#pragma unroll
        for (int n = 0; n < 4; ++n)
          acc[m][n] = __builtin_amdgcn_mfma_i32_16x16x64_i8(a[m], b[n], acc[m][n], 0, 0, 0);
    }
    __syncthreads();
  }

  float sDeq = (pAw[0] * pAin[0]) / (QMAX * QMAX);
#pragma unroll
  for (int n = 0; n < 4; ++n) {
    int gcol = bcolBase + wc + n * 16 + l15;
    int bv = bias[gcol];
#pragma unroll
    for (int m = 0; m < 4; ++m) {
      int growb = browBase + wr + m * 16 + (hi << 2);
#pragma unroll
      for (int r = 0; r < 4; ++r) {
        O[(size_t)(growb + r) * N + gcol] = (float)(acc[m][n][r] + bv) * sDeq;
      }
    }
  }
}

extern "C" void kernel_launch(void* const* d_in, const int* in_sizes, int n_in,
                              void* d_out, int out_size, void* d_ws, size_t ws_size,
                              hipStream_t stream) {
  const float* x     = (const float*)d_in[0];
  const float* a_in0 = (const float*)d_in[1];
  const float* a_w0  = (const float*)d_in[2];
  const float* a_in2 = (const float*)d_in[3];
  const float* a_w2  = (const float*)d_in[4];
  const float* a_in4 = (const float*)d_in[5];
  const float* a_w4  = (const float*)d_in[6];
  const int*   W0    = (const int*)d_in[7];
  const int*   W1    = (const int*)d_in[8];
  const int*   W2    = (const int*)d_in[9];
  float* out = (float*)d_out;

  constexpr int B = 4096, IN = 1024, H0 = 4096, H1 = 4096, OUTN = 1024;

  char* ws = (char*)d_ws;
  size_t off = 0;
  auto alloc = [&](size_t sz) {
    char* p = ws + off;
    off += (sz + 255) & ~(size_t)255;
    return p;
  };
  signed char* qa0 = (signed char*)alloc((size_t)B * IN);
  signed char* qa1 = (signed char*)alloc((size_t)B * H0);
  signed char* qa2 = (signed char*)alloc((size_t)B * H1);
  signed char* W0p = (signed char*)alloc((size_t)H0 * IN);
  signed char* W1p = (signed char*)alloc((size_t)H1 * H0);
  signed char* W2p = (signed char*)alloc((size_t)OUTN * H1);
  int* b0 = (int*)alloc((size_t)H0 * 4);
  int* b1 = (int*)alloc((size_t)H1 * 4);
  int* b2 = (int*)alloc((size_t)OUTN * 4);

  hipFuncSetAttribute((const void*)qgemm256_kernel,
                      hipFuncAttributeMaxDynamicSharedMemorySize, 131072);

  // merged prep: pack W0/W1/W2 + quantize x (1 launch, 28672 blocks)
  prep_kernel<<<28672, 256, 0, stream>>>(x, qa0, a_in0,
                                         W0, W0p, b0,
                                         W1, W1p, b1,
                                         W2, W2p, b2);

  // layer 0: [B,IN]x[H0,IN]^T -> qa1 (int8), grid 16x16=256
  qgemm256_kernel<<<(B / 256) * (H0 / 256), 512, 131072, stream>>>(
      qa0, W0p, b0, qa1, H0, IN, H0 / 256, a_in0, a_w0, a_in2);

  // layer 1: [B,H0]x[H1,H0]^T -> qa2 (int8), grid 16x16=256
  qgemm256_kernel<<<(B / 256) * (H1 / 256), 512, 131072, stream>>>(
      qa1, W1p, b1, qa2, H1, H0, H1 / 256, a_in2, a_w2, a_in4);

  // layer 2: [B,H1]x[OUT,H1]^T -> f32 out, 128^2 kernel, grid 32x8=256
  qgemm_kernel<<<(B / 128) * (OUTN / 128), 256, 0, stream>>>(
      qa2, W2p, b2, out, OUTN, H1, OUTN / 128, a_in4, a_w4);
}

// Round 5
// 142.921 us; speedup vs baseline: 1.0515x; 1.0515x over previous
//
#include <hip/hip_runtime.h>

#define QMAX 127.0f

typedef int v4i __attribute__((ext_vector_type(4)));

__device__ __forceinline__ void gload_lds16(const void* g, void* l) {
  __builtin_amdgcn_global_load_lds(
      (const __attribute__((address_space(1))) void*)g,
      (__attribute__((address_space(3))) void*)l, 16, 0, 0);
}

// ---------------- merged prep: pack W0/W1/W2 + quantize x (1 launch) --------
__device__ __forceinline__ void pack_body(const int* __restrict__ W,
                                          signed char* __restrict__ W8,
                                          int* __restrict__ bias,
                                          unsigned lblk, int kshift) {
  unsigned t = lblk * 256u + threadIdx.x;
  unsigned row = t >> kshift;
  unsigned j = t & ((1u << kshift) - 1u);
  unsigned K = 4u << kshift;
  size_t srcBase = (size_t)row * (size_t)(K + 1) + (size_t)j * 4;
  int c0 = W[srcBase + 0], c1 = W[srcBase + 1], c2 = W[srcBase + 2], c3 = W[srcBase + 3];
  unsigned packed = (unsigned)(c0 & 0xff) | ((unsigned)(c1 & 0xff) << 8) |
                    ((unsigned)(c2 & 0xff) << 16) | ((unsigned)(c3 & 0xff) << 24);
  reinterpret_cast<unsigned*>(W8)[t] = packed;
  if (j == 0) bias[row] = W[(size_t)row * (K + 1) + K];
}

__global__ void prep_kernel(const float* __restrict__ x,
                            signed char* __restrict__ qa0,
                            const float* __restrict__ pAin,
                            const int* __restrict__ W0, signed char* __restrict__ W0p, int* __restrict__ b0,
                            const int* __restrict__ W1, signed char* __restrict__ W1p, int* __restrict__ b1,
                            const int* __restrict__ W2, signed char* __restrict__ W2p, int* __restrict__ b2) {
  unsigned blk = blockIdx.x;
  if (blk < 4096u) {
    pack_body(W0, W0p, b0, blk, 8);
  } else if (blk < 20480u) {
    pack_body(W1, W1p, b1, blk - 4096u, 10);
  } else if (blk < 24576u) {
    pack_body(W2, W2p, b2, blk - 20480u, 10);
  } else {
    unsigned t = (blk - 24576u) * 256u + threadIdx.x;
    float s = QMAX / pAin[0];
    float4 v = reinterpret_cast<const float4*>(x)[t];
    int q0 = (int)fminf(fmaxf(rintf(v.x * s), -QMAX), QMAX);
    int q1 = (int)fminf(fmaxf(rintf(v.y * s), -QMAX), QMAX);
    int q2 = (int)fminf(fmaxf(rintf(v.z * s), -QMAX), QMAX);
    int q3 = (int)fminf(fmaxf(rintf(v.w * s), -QMAX), QMAX);
    unsigned packed = (unsigned)(q0 & 0xff) | ((unsigned)(q1 & 0xff) << 8) |
                      ((unsigned)(q2 & 0xff) << 16) | ((unsigned)(q3 & 0xff) << 24);
    reinterpret_cast<unsigned*>(qa0)[t] = packed;
  }
}

// =====================================================================
// 256x256-tile int8 GEMM, 16x16x64 MFMA, 4 MERGED phases per 2 K-tiles.
// 8 waves (2M x 4N), per-wave out 128x64, BK=128 B, LDS 128 KiB dbuf.
// Per phase: 32 MFMA cluster (one 64-row quadrant x full BK); 6 barriers
// per iteration (P1/P3 carry a visibility barrier after counted vmcnt(8);
// P2/P4 need none). WAR safety: every region is staged only after the
// phase whose LGK0 drained its final read:
//   b0.B read P1 -> staged P2 | b0.A read P1+P2 -> staged P3
//   b1.B read P3 -> staged P4 | b1.A read P3+P4 -> staged next-P1
// vmcnt: 12 loads in flight entering P1 (+4 issued) -> vmcnt(8) waits
// exactly for the opening tile's 8; same at P3. Never drained in-loop.
// =====================================================================

#define FENCE() asm volatile("" ::: "memory")
#define BARRIER()                      \
  do {                                 \
    FENCE();                           \
    __builtin_amdgcn_s_barrier();      \
    FENCE();                           \
  } while (0)
#define LGK0() asm volatile("s_waitcnt lgkmcnt(0)" ::: "memory")
#define VMC8() asm volatile("s_waitcnt vmcnt(8)" ::: "memory")
#define VMC0() asm volatile("s_waitcnt vmcnt(0)" ::: "memory")

#define STAGE_A(bf, h, t)                                                     \
  do {                                                                        \
    const signed char* _g = gA + (size_t)((h) * 128) * K + (size_t)(t) * 128; \
    signed char* _l = ldsA + (bf) * 32768 + (h) * 16384 + ldsThr;             \
    gload_lds16(_g, _l);                                                      \
    gload_lds16(_g + (size_t)8 * K, _l + 1024);                               \
  } while (0)

#define STAGE_B(bf, h, t)                                                     \
  do {                                                                        \
    const signed char* _g = gB + (size_t)((h) * 128) * K + (size_t)(t) * 128; \
    signed char* _l = ldsB + (bf) * 32768 + (h) * 16384 + ldsThr;             \
    gload_lds16(_g, _l);                                                      \
    gload_lds16(_g + (size_t)8 * K, _l + 1024);                               \
  } while (0)

// 8 ds_read_b128: A quadrant qm (4 m-frags x 2 k-halves) -> aq[m][kk]
#define LDAQ(bf, qm)                                                          \
  do {                                                                        \
    _Pragma("unroll") for (int m = 0; m < 4; ++m) {                           \
      int row = wm * 128 + (qm) * 64 + m * 16 + l15;                          \
      _Pragma("unroll") for (int kk = 0; kk < 2; ++kk) {                      \
        int off = (kk * 64 + hi * 16) ^ ((row & 7) << 4);                     \
        aq[m][kk] = *(const v4i*)(ldsA + (bf) * 32768 + row * 128 + off);     \
      }                                                                       \
    }                                                                         \
  } while (0)

// 8 ds_read_b128: B all n-frags x 2 k-halves -> bR[n][kk]
#define LDBF(bf)                                                              \
  do {                                                                        \
    _Pragma("unroll") for (int n = 0; n < 4; ++n) {                           \
      int row = wn * 64 + n * 16 + l15;                                       \
      _Pragma("unroll") for (int kk = 0; kk < 2; ++kk) {                      \
        int off = (kk * 64 + hi * 16) ^ ((row & 7) << 4);                     \
        bR[n][kk] = *(const v4i*)(ldsB + (bf) * 32768 + row * 128 + off);     \
      }                                                                       \
    }                                                                         \
  } while (0)

// 32 MFMA: quadrant qm, all n, both k-halves (A operands in aq)
#define MFMAC(qm)                                                             \
  do {                                                                        \
    __builtin_amdgcn_s_setprio(1);                                            \
    _Pragma("unroll") for (int m = 0; m < 4; ++m)                             \
    _Pragma("unroll") for (int n = 0; n < 4; ++n)                             \
    _Pragma("unroll") for (int kk = 0; kk < 2; ++kk)                          \
      acc[(qm) * 4 + m][n] = __builtin_amdgcn_mfma_i32_16x16x64_i8(           \
          aq[m][kk], bR[n][kk], acc[(qm) * 4 + m][n], 0, 0, 0);               \
    __builtin_amdgcn_s_setprio(0);                                            \
  } while (0)

__global__ __launch_bounds__(512, 2)
void qgemm256_kernel(const signed char* __restrict__ A,
                     const signed char* __restrict__ Bw,
                     const int* __restrict__ bias,
                     signed char* __restrict__ O,
                     int N, int K, int nbn,
                     const float* __restrict__ pAin,
                     const float* __restrict__ pAw,
                     const float* __restrict__ pAnext) {
  extern __shared__ signed char lds[];
  signed char* ldsA = lds;           // buf0 [0,32K), buf1 [32K,64K)
  signed char* ldsB = lds + 65536;

  const int nwg = gridDim.x, bid = blockIdx.x, per = nwg >> 3;
  const int swz = (bid & 7) * per + (bid >> 3);
  const int brow = swz / nbn, bcol = swz - brow * nbn;
  const int browBase = brow << 8, bcolBase = bcol << 8;

  const int tid = threadIdx.x;
  const int lane = tid & 63, l15 = lane & 15, hi = lane >> 4;
  const int wid = tid >> 6, wm = wid >> 2, wn = wid & 3;

  const int rloc = (wid << 4) + (lane >> 3);
  const int csrc = (lane & 7) ^ ((lane >> 3) & 7);
  const signed char* gA = A + (size_t)(browBase + rloc) * K + csrc * 16;
  const signed char* gB = Bw + (size_t)(bcolBase + rloc) * K + csrc * 16;
  const int ldsThr = (wid << 11) + lane * 16;

  v4i acc[8][4] = {};
  v4i bR[4][2];

  const int nk = K >> 7, niter = nk >> 1, nkm = nk - 1;

  // prologue: tile0 {B0,B1,A0,A1} (8 loads) + tile1 {B0,B1} (4 loads).
  // 12 in flight entering P1; P1 issues 4 more; vmcnt(8) = tile0 landed.
  STAGE_B(0, 0, 0); STAGE_B(0, 1, 0); STAGE_A(0, 0, 0); STAGE_A(0, 1, 0);
  STAGE_B(1, 0, 1); STAGE_B(1, 1, 1);

#pragma unroll 1
  for (int i = 0; i < niter; ++i) {
    const int t1 = 2 * i + 1;
    const int tE = (2 * i + 2) & nkm;   // wrapped: always issue (exact vmcnt)
    const int tO = (2 * i + 3) & nkm;
    v4i aq[4][2];
    // P1: stage b1.A (t1; b1.A reads drained prev-P4); open buf0.
    STAGE_A(1, 0, t1); STAGE_A(1, 1, t1);
    VMC8();
    BARRIER();
    LDAQ(0, 0); LDBF(0);
    MFMAC(0);
    LGK0();            // buf0.B reads drained before P2 stages buf0.B
    BARRIER();
    // P2: stage b0.B (tE); read buf0 q1; no leading barrier needed.
    STAGE_B(0, 0, tE); STAGE_B(0, 1, tE);
    LDAQ(0, 1);
    MFMAC(1);
    LGK0();            // buf0.A reads drained before P3 stages buf0.A
    BARRIER();
    // P3: stage b0.A (tE); open buf1.
    STAGE_A(0, 0, tE); STAGE_A(0, 1, tE);
    VMC8();
    BARRIER();
    LDAQ(1, 0); LDBF(1);
    MFMAC(0);
    LGK0();            // buf1.B reads drained before P4 stages buf1.B
    BARRIER();
    // P4: stage b1.B (tO); read buf1 q1.
    STAGE_B(1, 0, tO); STAGE_B(1, 1, tO);
    LDAQ(1, 1);
    MFMAC(1);
    LGK0();            // buf1.A reads drained before next-P1 stages buf1.A
    BARRIER();
  }

  VMC0();  // drain orphan prefetches before epilogue

  const float sDeq = (pAw[0] * pAin[0]) / (QMAX * QMAX);
  const float sQ = QMAX / pAnext[0];
#pragma unroll
  for (int nf = 0; nf < 4; ++nf) {
    const int gcol = bcolBase + wn * 64 + nf * 16 + l15;
    const int bv = bias[gcol];
#pragma unroll
    for (int mf = 0; mf < 8; ++mf) {
      const int gr = browBase + wm * 128 + mf * 16 + (hi << 2);
#pragma unroll
      for (int r = 0; r < 4; ++r) {
        float f = (float)(acc[mf][nf][r] + bv) * sDeq;
        f = fmaxf(f, 0.0f);
        float qf = fminf(fmaxf(rintf(f * sQ), -QMAX), QMAX);
        O[(size_t)(gr + r) * N + gcol] = (signed char)(int)qf;
      }
    }
  }
}

// ---------------- 128x128-tile 2-barrier int8 GEMM (layer 2, f32 out) -------
__global__ __launch_bounds__(256)
void qgemm_kernel(const signed char* __restrict__ A,
                  const signed char* __restrict__ Bw,
                  const int* __restrict__ bias,
                  float* __restrict__ O,
                  int N, int K, int nbn,
                  const float* __restrict__ pAin,
                  const float* __restrict__ pAw) {
  __shared__ signed char slds[32768];
  signed char* ldsA = slds;
  signed char* ldsB = slds + 16384;

  int nwg = gridDim.x;
  int bid = blockIdx.x;
  int per = nwg >> 3;
  int swz = (bid & 7) * per + (bid >> 3);
  int brow = swz / nbn;
  int bcol = swz - brow * nbn;
  int browBase = brow << 7;
  int bcolBase = bcol << 7;

  int tid = threadIdx.x;
  int lane = tid & 63;
  int l15 = lane & 15;
  int hi = lane >> 4;
  int wid = tid >> 6;
  int wr = (wid >> 1) << 6;
  int wc = (wid & 1) << 6;

  v4i acc[4][4] = {};

  int nk = K >> 7;
  for (int kt = 0; kt < nk; ++kt) {
    int k0 = kt << 7;
#pragma unroll
    for (int i = 0; i < 4; ++i) {
      int c = i * 256 + tid;
      int r = c >> 3;
      int osrc = ((c & 7) << 4) ^ ((r & 7) << 4);
      gload_lds16(A + (size_t)(browBase + r) * K + (k0 + osrc), ldsA + c * 16);
      gload_lds16(Bw + (size_t)(bcolBase + r) * K + (k0 + osrc), ldsB + c * 16);
    }
    __syncthreads();
#pragma unroll
    for (int kk = 0; kk < 2; ++kk) {
      v4i a[4], b[4];
#pragma unroll
      for (int m = 0; m < 4; ++m) {
        int row = wr + m * 16 + l15;
        int off = (kk * 64 + hi * 16) ^ ((row & 7) << 4);
        a[m] = *reinterpret_cast<const v4i*>(ldsA + row * 128 + off);
      }
#pragma unroll
      for (int n = 0; n < 4; ++n) {
        int row = wc + n * 16 + l15;
        int off = (kk * 64 + hi * 16) ^ ((row & 7) << 4);
        b[n] = *reinterpret_cast<const v4i*>(ldsB + row * 128 + off);
      }
#pragma unroll
      for (int m = 0; m < 4; ++m)
#pragma unroll
        for (int n = 0; n < 4; ++n)
          acc[m][n] = __builtin_amdgcn_mfma_i32_16x16x64_i8(a[m], b[n], acc[m][n], 0, 0, 0);
    }
    __syncthreads();
  }

  float sDeq = (pAw[0] * pAin[0]) / (QMAX * QMAX);
#pragma unroll
  for (int n = 0; n < 4; ++n) {
    int gcol = bcolBase + wc + n * 16 + l15;
    int bv = bias[gcol];
#pragma unroll
    for (int m = 0; m < 4; ++m) {
      int growb = browBase + wr + m * 16 + (hi << 2);
#pragma unroll
      for (int r = 0; r < 4; ++r) {
        O[(size_t)(growb + r) * N + gcol] = (float)(acc[m][n][r] + bv) * sDeq;
      }
    }
  }
}

extern "C" void kernel_launch(void* const* d_in, const int* in_sizes, int n_in,
                              void* d_out, int out_size, void* d_ws, size_t ws_size,
                              hipStream_t stream) {
  const float* x     = (const float*)d_in[0];
  const float* a_in0 = (const float*)d_in[1];
  const float* a_w0  = (const float*)d_in[2];
  const float* a_in2 = (const float*)d_in[3];
  const float* a_w2  = (const float*)d_in[4];
  const float* a_in4 = (const float*)d_in[5];
  const float* a_w4  = (const float*)d_in[6];
  const int*   W0    = (const int*)d_in[7];
  const int*   W1    = (const int*)d_in[8];
  const int*   W2    = (const int*)d_in[9];
  float* out = (float*)d_out;

  constexpr int B = 4096, IN = 1024, H0 = 4096, H1 = 4096, OUTN = 1024;

  char* ws = (char*)d_ws;
  size_t off = 0;
  auto alloc = [&](size_t sz) {
    char* p = ws + off;
    off += (sz + 255) & ~(size_t)255;
    return p;
  };
  signed char* qa0 = (signed char*)alloc((size_t)B * IN);
  signed char* qa1 = (signed char*)alloc((size_t)B * H0);
  signed char* qa2 = (signed char*)alloc((size_t)B * H1);
  signed char* W0p = (signed char*)alloc((size_t)H0 * IN);
  signed char* W1p = (signed char*)alloc((size_t)H1 * H0);
  signed char* W2p = (signed char*)alloc((size_t)OUTN * H1);
  int* b0 = (int*)alloc((size_t)H0 * 4);
  int* b1 = (int*)alloc((size_t)H1 * 4);
  int* b2 = (int*)alloc((size_t)OUTN * 4);

  hipFuncSetAttribute((const void*)qgemm256_kernel,
                      hipFuncAttributeMaxDynamicSharedMemorySize, 131072);

  // merged prep: pack W0/W1/W2 + quantize x (1 launch, 28672 blocks)
  prep_kernel<<<28672, 256, 0, stream>>>(x, qa0, a_in0,
                                         W0, W0p, b0,
                                         W1, W1p, b1,
                                         W2, W2p, b2);

  // layer 0: [B,IN]x[H0,IN]^T -> qa1 (int8), grid 16x16=256
  qgemm256_kernel<<<(B / 256) * (H0 / 256), 512, 131072, stream>>>(
      qa0, W0p, b0, qa1, H0, IN, H0 / 256, a_in0, a_w0, a_in2);

  // layer 1: [B,H0]x[H1,H0]^T -> qa2 (int8), grid 16x16=256
  qgemm256_kernel<<<(B / 256) * (H1 / 256), 512, 131072, stream>>>(
      qa1, W1p, b1, qa2, H1, H0, H1 / 256, a_in2, a_w2, a_in4);

  // layer 2: [B,H1]x[OUT,H1]^T -> f32 out, 128^2 kernel, grid 32x8=256
  qgemm_kernel<<<(B / 128) * (OUTN / 128), 256, 0, stream>>>(
      qa2, W2p, b2, out, OUTN, H1, OUTN / 128, a_in4, a_w4);
}

// Round 6
// 139.944 us; speedup vs baseline: 1.0739x; 1.0213x over previous
//
#include <hip/hip_runtime.h>

#define QMAX 127.0f

typedef int v4i __attribute__((ext_vector_type(4)));

__device__ __forceinline__ void gload_lds16(const void* g, void* l) {
  __builtin_amdgcn_global_load_lds(
      (const __attribute__((address_space(1))) void*)g,
      (__attribute__((address_space(3))) void*)l, 16, 0, 0);
}

// ---------------- merged prep: pack W0/W1/W2 + quantize x (1 launch) --------
__device__ __forceinline__ void pack_body(const int* __restrict__ W,
                                          signed char* __restrict__ W8,
                                          int* __restrict__ bias,
                                          unsigned lblk, int kshift) {
  unsigned t = lblk * 256u + threadIdx.x;
  unsigned row = t >> kshift;
  unsigned j = t & ((1u << kshift) - 1u);
  unsigned K = 4u << kshift;
  size_t srcBase = (size_t)row * (size_t)(K + 1) + (size_t)j * 4;
  int c0 = W[srcBase + 0], c1 = W[srcBase + 1], c2 = W[srcBase + 2], c3 = W[srcBase + 3];
  unsigned packed = (unsigned)(c0 & 0xff) | ((unsigned)(c1 & 0xff) << 8) |
                    ((unsigned)(c2 & 0xff) << 16) | ((unsigned)(c3 & 0xff) << 24);
  reinterpret_cast<unsigned*>(W8)[t] = packed;
  if (j == 0) bias[row] = W[(size_t)row * (K + 1) + K];
}

__global__ void prep_kernel(const float* __restrict__ x,
                            signed char* __restrict__ qa0,
                            const float* __restrict__ pAin,
                            const int* __restrict__ W0, signed char* __restrict__ W0p, int* __restrict__ b0,
                            const int* __restrict__ W1, signed char* __restrict__ W1p, int* __restrict__ b1,
                            const int* __restrict__ W2, signed char* __restrict__ W2p, int* __restrict__ b2) {
  unsigned blk = blockIdx.x;
  if (blk < 4096u) {
    pack_body(W0, W0p, b0, blk, 8);
  } else if (blk < 20480u) {
    pack_body(W1, W1p, b1, blk - 4096u, 10);
  } else if (blk < 24576u) {
    pack_body(W2, W2p, b2, blk - 20480u, 10);
  } else {
    unsigned t = (blk - 24576u) * 256u + threadIdx.x;
    float s = QMAX / pAin[0];
    float4 v = reinterpret_cast<const float4*>(x)[t];
    int q0 = (int)fminf(fmaxf(rintf(v.x * s), -QMAX), QMAX);
    int q1 = (int)fminf(fmaxf(rintf(v.y * s), -QMAX), QMAX);
    int q2 = (int)fminf(fmaxf(rintf(v.z * s), -QMAX), QMAX);
    int q3 = (int)fminf(fmaxf(rintf(v.w * s), -QMAX), QMAX);
    unsigned packed = (unsigned)(q0 & 0xff) | ((unsigned)(q1 & 0xff) << 8) |
                      ((unsigned)(q2 & 0xff) << 16) | ((unsigned)(q3 & 0xff) << 24);
    reinterpret_cast<unsigned*>(qa0)[t] = packed;
  }
}

// =====================================================================
// 256x256-tile int8 GEMM, k-split 2-phase with 1-cluster register
// lookahead. Per K-tile: PH_K0 (cluster k0) + PH_K1 (cluster k1).
// Every MFMA cluster's operands were read >= 1 phase earlier (A) or
// drained by a COUNTED lgkmcnt that leaves the 8 lookahead A-reads in
// flight (no lgkmcnt(0) anywhere in steady state). Stage = full tile
// (8 gloads) in PH_K0; WAR safe because the evicted tile's last reads
// (its B-k1, consumed by the previous MFMA) were drained by that
// cluster's pre-MFMA counted wait, before this phase's barrier.
// RAW: vmcnt(0) -> barrier in PH_K1 (stages issued 1 phase earlier).
// =====================================================================

#define FENCE() asm volatile("" ::: "memory")
#define BARRIER()                      \
  do {                                 \
    FENCE();                           \
    __builtin_amdgcn_s_barrier();      \
    FENCE();                           \
  } while (0)
#define LGK(n) asm volatile("s_waitcnt lgkmcnt(" #n ")" ::: "memory")
#define VMC0() asm volatile("s_waitcnt vmcnt(0)" ::: "memory")

#define STAGE_A(bf, h, t)                                                     \
  do {                                                                        \
    const signed char* _g = gA + (size_t)((h) * 128) * K + (size_t)(t) * 128; \
    signed char* _l = ldsA + (bf) * 32768 + (h) * 16384 + ldsThr;             \
    gload_lds16(_g, _l);                                                      \
    gload_lds16(_g + (size_t)8 * K, _l + 1024);                               \
  } while (0)

#define STAGE_B(bf, h, t)                                                     \
  do {                                                                        \
    const signed char* _g = gB + (size_t)((h) * 128) * K + (size_t)(t) * 128; \
    signed char* _l = ldsB + (bf) * 32768 + (h) * 16384 + ldsThr;             \
    gload_lds16(_g, _l);                                                      \
    gload_lds16(_g + (size_t)8 * K, _l + 1024);                               \
  } while (0)

#define STAGE_T(bf, t)                                                        \
  do {                                                                        \
    STAGE_A(bf, 0, t); STAGE_A(bf, 1, t);                                     \
    STAGE_B(bf, 0, t); STAGE_B(bf, 1, t);                                     \
  } while (0)

// 8 ds_read_b128: all A m-frags for k-half kk -> dst[0..7]
#define LDA8(bf, kk, dst)                                                     \
  do {                                                                        \
    _Pragma("unroll") for (int m = 0; m < 8; ++m) {                           \
      int row = wm * 128 + m * 16 + l15;                                      \
      int off = ((kk) * 64 + hi * 16) ^ ((l15 & 7) << 4);                     \
      dst[m] = *(const v4i*)(ldsA + (bf) * 32768 + row * 128 + off);          \
    }                                                                         \
  } while (0)

// 4 ds_read_b128: all B n-frags for k-half kk -> bK[0..3]
#define LDB4(bf, kk)                                                          \
  do {                                                                        \
    _Pragma("unroll") for (int n = 0; n < 4; ++n) {                           \
      int row = wn * 64 + n * 16 + l15;                                       \
      int off = ((kk) * 64 + hi * 16) ^ ((l15 & 7) << 4);                     \
      bK[n] = *(const v4i*)(ldsB + (bf) * 32768 + row * 128 + off);           \
    }                                                                         \
  } while (0)

// 32 MFMA: all m x all n for one k-half (A operands in aset, B in bK)
#define MFMA32(aset)                                                          \
  do {                                                                        \
    __builtin_amdgcn_s_setprio(1);                                            \
    _Pragma("unroll") for (int m = 0; m < 8; ++m)                             \
    _Pragma("unroll") for (int n = 0; n < 4; ++n)                             \
      acc[m][n] = __builtin_amdgcn_mfma_i32_16x16x64_i8(                      \
          aset[m], bK[n], acc[m][n], 0, 0, 0);                                \
    __builtin_amdgcn_s_setprio(0);                                            \
  } while (0)

__global__ __launch_bounds__(512, 2)
void qgemm256_kernel(const signed char* __restrict__ A,
                     const signed char* __restrict__ Bw,
                     const int* __restrict__ bias,
                     signed char* __restrict__ O,
                     int N, int K, int nbn,
                     const float* __restrict__ pAin,
                     const float* __restrict__ pAw,
                     const float* __restrict__ pAnext) {
  extern __shared__ signed char lds[];
  signed char* ldsA = lds;           // buf0 [0,32K), buf1 [32K,64K)
  signed char* ldsB = lds + 65536;

  const int nwg = gridDim.x, bid = blockIdx.x, per = nwg >> 3;
  const int swz = (bid & 7) * per + (bid >> 3);
  const int brow = swz / nbn, bcol = swz - brow * nbn;
  const int browBase = brow << 8, bcolBase = bcol << 8;

  const int tid = threadIdx.x;
  const int lane = tid & 63, l15 = lane & 15, hi = lane >> 4;
  const int wid = tid >> 6, wm = wid >> 2, wn = wid & 3;

  const int rloc = (wid << 4) + (lane >> 3);
  const int csrc = (lane & 7) ^ ((lane >> 3) & 7);
  const signed char* gA = A + (size_t)(browBase + rloc) * K + csrc * 16;
  const signed char* gB = Bw + (size_t)(bcolBase + rloc) * K + csrc * 16;
  const int ldsThr = (wid << 11) + lane * 16;

  v4i acc[8][4] = {};
  v4i aK0[8], aK1[8], bK[4];

  const int nk = K >> 7, niter = nk >> 1, nkm = nk - 1;

  // prologue: stage tile0 -> buf0, open it, preload A-k0(0)
  STAGE_T(0, 0);
  VMC0();
  BARRIER();
  LDA8(0, 0, aK0);

#pragma unroll 1
  for (int i = 0; i < niter; ++i) {
    const int tO = 2 * i + 1;           // odd tile -> buf1
    const int tE = (2 * i + 2) & nkm;   // next even tile -> buf0 (wraps once)
    // ======== tile 2i (buf0) ========
    // PH_K0: stage tile tO -> buf1 (buf1's old reads fully drained);
    //        reads: B-k0(cur) + A-k1 lookahead; MFMA C_k0 (deps: aK0 + bK)
    LGK(8);                 // safety (outstanding = 8 lookahead A-reads)
    BARRIER();
    STAGE_T(1, tO);
    LDB4(0, 0); FENCE(); LDA8(0, 1, aK1);
    LGK(8);                 // drains aK0 + bK, leaves aK1 in flight
    MFMA32(aK0);
    // PH_K1: tile tO staged -> visible; reads B-k1(cur) + A-k0(tO) lookahead
    VMC0();
    BARRIER();
    LDB4(0, 1); FENCE(); LDA8(1, 0, aK0);
    LGK(8);                 // drains aK1 + bK, leaves aK0' in flight
    MFMA32(aK1);
    // ======== tile 2i+1 (buf1) ========
    LGK(8);
    BARRIER();
    STAGE_T(0, tE);
    LDB4(1, 0); FENCE(); LDA8(1, 1, aK1);
    LGK(8);
    MFMA32(aK0);
    VMC0();
    BARRIER();
    LDB4(1, 1); FENCE(); LDA8(0, 0, aK0);
    LGK(8);
    MFMA32(aK1);
  }

  VMC0();  // drain any orphan prefetch before epilogue

  const float sDeq = (pAw[0] * pAin[0]) / (QMAX * QMAX);
  const float sQ = QMAX / pAnext[0];
#pragma unroll
  for (int nf = 0; nf < 4; ++nf) {
    const int gcol = bcolBase + wn * 64 + nf * 16 + l15;
    const int bv = bias[gcol];
#pragma unroll
    for (int mf = 0; mf < 8; ++mf) {
      const int gr = browBase + wm * 128 + mf * 16 + (hi << 2);
#pragma unroll
      for (int r = 0; r < 4; ++r) {
        float f = (float)(acc[mf][nf][r] + bv) * sDeq;
        f = fmaxf(f, 0.0f);
        float qf = fminf(fmaxf(rintf(f * sQ), -QMAX), QMAX);
        O[(size_t)(gr + r) * N + gcol] = (signed char)(int)qf;
      }
    }
  }
}

// ---------------- 128x128-tile k-split 2-phase int8 GEMM (layer 2) ----------
#define STG128(bf, t)                                                         \
  do {                                                                        \
    _Pragma("unroll") for (int ii = 0; ii < 4; ++ii) {                        \
      int c = ii * 256 + tid;                                                 \
      int r = c >> 3;                                                         \
      int osrc = ((c & 7) << 4) ^ ((r & 7) << 4);                             \
      gload_lds16(A + (size_t)(browBase + r) * K + ((t) * 128 + osrc),        \
                  ldsA + (bf) * 16384 + c * 16);                              \
      gload_lds16(Bw + (size_t)(bcolBase + r) * K + ((t) * 128 + osrc),       \
                  ldsB + (bf) * 16384 + c * 16);                              \
    }                                                                         \
  } while (0)

#define LDA4_128(bf, kk, dst)                                                 \
  do {                                                                        \
    _Pragma("unroll") for (int m = 0; m < 4; ++m) {                           \
      int row = wr + m * 16 + l15;                                            \
      int off = ((kk) * 64 + hi * 16) ^ ((l15 & 7) << 4);                     \
      dst[m] = *(const v4i*)(ldsA + (bf) * 16384 + row * 128 + off);          \
    }                                                                         \
  } while (0)

#define LDB4_128(bf, kk)                                                      \
  do {                                                                        \
    _Pragma("unroll") for (int n = 0; n < 4; ++n) {                           \
      int row = wc + n * 16 + l15;                                            \
      int off = ((kk) * 64 + hi * 16) ^ ((l15 & 7) << 4);                     \
      bK[n] = *(const v4i*)(ldsB + (bf) * 16384 + row * 128 + off);           \
    }                                                                         \
  } while (0)

#define MFMA16(aset)                                                          \
  do {                                                                        \
    __builtin_amdgcn_s_setprio(1);                                            \
    _Pragma("unroll") for (int m = 0; m < 4; ++m)                             \
    _Pragma("unroll") for (int n = 0; n < 4; ++n)                             \
      acc[m][n] = __builtin_amdgcn_mfma_i32_16x16x64_i8(                      \
          aset[m], bK[n], acc[m][n], 0, 0, 0);                                \
    __builtin_amdgcn_s_setprio(0);                                            \
  } while (0)

__global__ __launch_bounds__(256)
void qgemm_kernel(const signed char* __restrict__ A,
                  const signed char* __restrict__ Bw,
                  const int* __restrict__ bias,
                  float* __restrict__ O,
                  int N, int K, int nbn,
                  const float* __restrict__ pAin,
                  const float* __restrict__ pAw) {
  __shared__ signed char slds[65536];
  signed char* ldsA = slds;            // bufs at 0 / 16K
  signed char* ldsB = slds + 32768;    // bufs at 0 / 16K

  const int nwg = gridDim.x, bid = blockIdx.x, per = nwg >> 3;
  const int swz = (bid & 7) * per + (bid >> 3);
  const int brow = swz / nbn, bcol = swz - brow * nbn;
  const int browBase = brow << 7, bcolBase = bcol << 7;

  const int tid = threadIdx.x;
  const int lane = tid & 63, l15 = lane & 15, hi = lane >> 4;
  const int wid = tid >> 6;
  const int wr = (wid >> 1) << 6, wc = (wid & 1) << 6;

  v4i acc[4][4] = {};
  v4i aK0[4], aK1[4], bK[4];

  const int nk = K >> 7, niter = nk >> 1, nkm = nk - 1;

  STG128(0, 0);
  VMC0();
  BARRIER();
  LDA4_128(0, 0, aK0);

#pragma unroll 1
  for (int i = 0; i < niter; ++i) {
    const int tO = 2 * i + 1;
    const int tE = (2 * i + 2) & nkm;
    // tile 2i (buf0)
    LGK(4);
    BARRIER();
    STG128(1, tO);
    LDB4_128(0, 0); FENCE(); LDA4_128(0, 1, aK1);
    LGK(4);
    MFMA16(aK0);
    VMC0();
    BARRIER();
    LDB4_128(0, 1); FENCE(); LDA4_128(1, 0, aK0);
    LGK(4);
    MFMA16(aK1);
    // tile 2i+1 (buf1)
    LGK(4);
    BARRIER();
    STG128(0, tE);
    LDB4_128(1, 0); FENCE(); LDA4_128(1, 1, aK1);
    LGK(4);
    MFMA16(aK0);
    VMC0();
    BARRIER();
    LDB4_128(1, 1); FENCE(); LDA4_128(0, 0, aK0);
    LGK(4);
    MFMA16(aK1);
  }

  VMC0();

  const float sDeq = (pAw[0] * pAin[0]) / (QMAX * QMAX);
#pragma unroll
  for (int n = 0; n < 4; ++n) {
    int gcol = bcolBase + wc + n * 16 + l15;
    int bv = bias[gcol];
#pragma unroll
    for (int m = 0; m < 4; ++m) {
      int growb = browBase + wr + m * 16 + (hi << 2);
#pragma unroll
      for (int r = 0; r < 4; ++r) {
        O[(size_t)(growb + r) * N + gcol] = (float)(acc[m][n][r] + bv) * sDeq;
      }
    }
  }
}

extern "C" void kernel_launch(void* const* d_in, const int* in_sizes, int n_in,
                              void* d_out, int out_size, void* d_ws, size_t ws_size,
                              hipStream_t stream) {
  const float* x     = (const float*)d_in[0];
  const float* a_in0 = (const float*)d_in[1];
  const float* a_w0  = (const float*)d_in[2];
  const float* a_in2 = (const float*)d_in[3];
  const float* a_w2  = (const float*)d_in[4];
  const float* a_in4 = (const float*)d_in[5];
  const float* a_w4  = (const float*)d_in[6];
  const int*   W0    = (const int*)d_in[7];
  const int*   W1    = (const int*)d_in[8];
  const int*   W2    = (const int*)d_in[9];
  float* out = (float*)d_out;

  constexpr int B = 4096, IN = 1024, H0 = 4096, H1 = 4096, OUTN = 1024;

  char* ws = (char*)d_ws;
  size_t off = 0;
  auto alloc = [&](size_t sz) {
    char* p = ws + off;
    off += (sz + 255) & ~(size_t)255;
    return p;
  };
  signed char* qa0 = (signed char*)alloc((size_t)B * IN);
  signed char* qa1 = (signed char*)alloc((size_t)B * H0);
  signed char* qa2 = (signed char*)alloc((size_t)B * H1);
  signed char* W0p = (signed char*)alloc((size_t)H0 * IN);
  signed char* W1p = (signed char*)alloc((size_t)H1 * H0);
  signed char* W2p = (signed char*)alloc((size_t)OUTN * H1);
  int* b0 = (int*)alloc((size_t)H0 * 4);
  int* b1 = (int*)alloc((size_t)H1 * 4);
  int* b2 = (int*)alloc((size_t)OUTN * 4);

  hipFuncSetAttribute((const void*)qgemm256_kernel,
                      hipFuncAttributeMaxDynamicSharedMemorySize, 131072);

  // merged prep: pack W0/W1/W2 + quantize x (1 launch, 28672 blocks)
  prep_kernel<<<28672, 256, 0, stream>>>(x, qa0, a_in0,
                                         W0, W0p, b0,
                                         W1, W1p, b1,
                                         W2, W2p, b2);

  // layer 0: [B,IN]x[H0,IN]^T -> qa1 (int8), grid 16x16=256
  qgemm256_kernel<<<(B / 256) * (H0 / 256), 512, 131072, stream>>>(
      qa0, W0p, b0, qa1, H0, IN, H0 / 256, a_in0, a_w0, a_in2);

  // layer 1: [B,H0]x[H1,H0]^T -> qa2 (int8), grid 16x16=256
  qgemm256_kernel<<<(B / 256) * (H1 / 256), 512, 131072, stream>>>(
      qa1, W1p, b1, qa2, H1, H0, H1 / 256, a_in2, a_w2, a_in4);

  // layer 2: [B,H1]x[OUT,H1]^T -> f32 out, 128^2 k-split, grid 32x8=256
  qgemm_kernel<<<(B / 128) * (OUTN / 128), 256, 0, stream>>>(
      qa2, W2p, b2, out, OUTN, H1, OUTN / 128, a_in4, a_w4);
}